// Round 21
// baseline (380.043 us; speedup 1.0000x reference)
//
#include <hip/hip_runtime.h>
#include <hip/hip_bf16.h>
#include <math.h>

#define S_LEN 4096
#define HID 768
#define NHEAD 12
#define NLAYER 2
#define WIN 256
#define FF 3072
#define N_ICD 8000
#define N_CPT 5000
#define N_CH 22

typedef short s16x8 __attribute__((ext_vector_type(8)));
typedef float fx4 __attribute__((ext_vector_type(4)));

__device__ __forceinline__ ushort f2bf(float f) {
    union { float f; uint u; } c; c.f = f;
    uint u = c.u + 0x7fffu + ((c.u >> 16) & 1u);
    return (ushort)(u >> 16);
}
__device__ __forceinline__ float bf2f(ushort u) {
    union { uint u; float f; } c; c.u = (uint)u << 16; return c.f;
}

// async global->LDS, 16B per lane; l must be the wave-uniform base (HW adds lane*16)
__device__ __forceinline__ void gld_lds16(const ushort* g, ushort* l) {
    __builtin_amdgcn_global_load_lds(
        (const __attribute__((address_space(1))) unsigned int*)g,
        (__attribute__((address_space(3))) unsigned int*)l, 16, 0, 0);
}

// bijective XCD-chunk swizzle (m204)
__device__ __forceinline__ int xcd_swizzle(int bid, int nwg) {
    int q = nwg >> 3, r = nwg & 7;
    int xcd = bid & 7, idx = bid >> 3;
    return (xcd < r ? xcd * (q + 1) : r * (q + 1) + (xcd - r) * q) + idx;
}

// ---------------- block reduce (deterministic), 256 threads ----------------
__device__ __forceinline__ float breduce(float v, volatile float* red) {
    int t = threadIdx.x;
    #pragma unroll
    for (int o = 32; o > 0; o >>= 1) v += __shfl_down(v, o, 64);
    __syncthreads();
    if ((t & 63) == 0) red[t >> 6] = v;
    __syncthreads();
    return red[0] + red[1] + red[2] + red[3];
}

#define QSCALE 0.1803368801111204f   // 0.125 * log2(e): folded scale for exp2-softmax
#define DEFER_THR 11.5415603f        // 8 * log2(e)

// ---------------- unified prep: weight transposes + bias pack + embed+LN ----------------
// flat 1D grid, exact block counts:
//  [0,4608)        qkvo transposes (8 x 576)
//  [4608,9216)     Wi transposes   (2 x 2304)
//  [9216,13824)    Wo2 transposes  (2 x 2304)
//  [13824,13830)   bias pack       (2 layers x 3)
//  [13830,17926)   embed + LN      (4096 rows)
__global__ __launch_bounds__(256) void prep_kernel(
    const float* __restrict__ Wq, const float* __restrict__ Wk,
    const float* __restrict__ Wv, const float* __restrict__ Wo_,
    const float* __restrict__ Wi, const float* __restrict__ Wo2,
    const float* __restrict__ bq, const float* __restrict__ bk,
    const float* __restrict__ bv,
    ushort* __restrict__ wt_qkvo, ushort* __restrict__ wt_i,
    ushort* __restrict__ wt_o2, float* __restrict__ bqkv,
    const int* __restrict__ ids, const float* __restrict__ we,
    const float* __restrict__ pe, const float* __restrict__ els,
    const float* __restrict__ elb, ushort* __restrict__ xb) {
    const size_t WW = (size_t)HID * HID;
    const size_t WI = (size_t)HID * FF;
    int idx = blockIdx.x;
    int t = threadIdx.x;
    __shared__ float T[32][33];
    __shared__ float red[4];
    if (idx >= 13830) {
        int srow = idx - 13830;
        int id = ids[srow];
        float v[3];
        #pragma unroll
        for (int i = 0; i < 3; i++) {
            int hh = i * 256 + t;
            v[i] = we[(size_t)id * HID + hh] + pe[srow * HID + hh];
        }
        float mean = breduce(v[0] + v[1] + v[2], red) * (1.f / HID);
        __syncthreads();
        float sq = 0.f;
        #pragma unroll
        for (int i = 0; i < 3; i++) { float d = v[i] - mean; sq += d * d; }
        float var = breduce(sq, red) * (1.f / HID);
        float inv = rsqrtf(var + 1e-5f);
        #pragma unroll
        for (int i = 0; i < 3; i++) {
            int hh = i * 256 + t;
            float o = (v[i] - mean) * inv * els[hh] + elb[hh];
            xb[(size_t)srow * HID + hh] = f2bf(o);
        }
        return;
    }
    if (idx >= 13824) {
        int b = idx - 13824;
        int l = b / 3, p = b % 3;
        int i = p * 256 + t;
        if (i < HID) {
            bqkv[l * 2304 + i]           = bq[l * HID + i] * QSCALE;   // scale folded
            bqkv[l * 2304 + HID + i]     = bk[l * HID + i];
            bqkv[l * 2304 + 2 * HID + i] = bv[l * HID + i];
        }
        return;
    }
    const float* in; ushort* out; int K, N, n0, k0;
    float wscale = 1.f;
    if (idx < 4608) {
        int z = idx / 576, r = idx % 576;
        int wsel = z >> 1, l = z & 1;
        in = (wsel == 0 ? Wq : wsel == 1 ? Wk : wsel == 2 ? Wv : Wo_) + (size_t)l * WW;
        out = wt_qkvo + ((size_t)l * 4 + wsel) * WW;
        K = HID; N = HID; n0 = (r % 24) * 32; k0 = (r / 24) * 32;
        if (wsel == 0) wscale = QSCALE;
    } else if (idx < 9216) {
        int r = idx - 4608; int l = r / 2304; r %= 2304;
        in = Wi + (size_t)l * WI; out = wt_i + (size_t)l * WI;
        K = HID; N = FF; n0 = (r % 96) * 32; k0 = (r / 96) * 32;
    } else {
        int r = idx - 9216; int l = r / 2304; r %= 2304;
        in = Wo2 + (size_t)l * WI; out = wt_o2 + (size_t)l * WI;
        K = FF; N = HID; n0 = (r % 24) * 32; k0 = (r / 24) * 32;
    }
    int tx = t & 31, ty = t >> 5;
    #pragma unroll
    for (int i = 0; i < 32; i += 8)
        T[ty + i][tx] = in[(size_t)(k0 + ty + i) * N + n0 + tx];
    __syncthreads();
    #pragma unroll
    for (int i = 0; i < 32; i += 8)
        out[(size_t)(n0 + ty + i) * K + k0 + tx] = f2bf(T[tx][ty + i] * wscale);
}

// ---------------- residual + LN, bf16 stream + 2 partials, wave-per-row, 4 rows/block ----------------
__global__ __launch_bounds__(256) void residual_ln_kernel(
    ushort* __restrict__ xb, const ushort* __restrict__ y0,
    const ushort* __restrict__ y1,
    const float* __restrict__ ls, const float* __restrict__ lb) {
    int row = blockIdx.x * 4 + (threadIdx.x >> 6);
    int lane = threadIdx.x & 63;
    const size_t base = (size_t)row * HID;
    float v[12];
    float s = 0.f;
    #pragma unroll
    for (int i = 0; i < 3; i++) {
        int c = i * 256 + lane * 4;
        ushort4 xv = *(const ushort4*)&xb[base + c];
        ushort4 av = *(const ushort4*)&y0[base + c];
        ushort4 bv = *(const ushort4*)&y1[base + c];
        v[i*4+0] = bf2f(xv.x) + (bf2f(av.x) + bf2f(bv.x));
        v[i*4+1] = bf2f(xv.y) + (bf2f(av.y) + bf2f(bv.y));
        v[i*4+2] = bf2f(xv.z) + (bf2f(av.z) + bf2f(bv.z));
        v[i*4+3] = bf2f(xv.w) + (bf2f(av.w) + bf2f(bv.w));
        s += (v[i*4+0] + v[i*4+1]) + (v[i*4+2] + v[i*4+3]);
    }
    #pragma unroll
    for (int o = 32; o > 0; o >>= 1) s += __shfl_down(s, o, 64);
    float mean = __shfl(s, 0, 64) * (1.f / HID);
    float sq = 0.f;
    #pragma unroll
    for (int i = 0; i < 12; i++) { v[i] -= mean; sq += v[i] * v[i]; }
    #pragma unroll
    for (int o = 32; o > 0; o >>= 1) sq += __shfl_down(sq, o, 64);
    float inv = rsqrtf(__shfl(sq, 0, 64) * (1.f / HID) + 1e-5f);
    #pragma unroll
    for (int i = 0; i < 3; i++) {
        int c = i * 256 + lane * 4;
        float4 sv = *(const float4*)&ls[c];
        float4 bv_ = *(const float4*)&lb[c];
        ushort4 ov;
        ov.x = f2bf(v[i*4+0] * inv * sv.x + bv_.x);
        ov.y = f2bf(v[i*4+1] * inv * sv.y + bv_.y);
        ov.z = f2bf(v[i*4+2] * inv * sv.z + bv_.z);
        ov.w = f2bf(v[i*4+3] * inv * sv.w + bv_.w);
        *(ushort4*)&xb[base + c] = ov;
    }
}

// ---------------- bf16 MFMA GEMM, global_load_lds staging, BK=64, XCD swizzle ----------------
// 4 waves 2x2; BM=BN=64: each wave 32x32. Single-buffer.
// gridDim.z = NSPLIT: block z computes K-range [z*K/nz, (z+1)*K/nz) into partial buffer z.
// Bias added by split 0 only. ACT must be 0 when NSPLIT > 1.
template<int BM, int BN, int ACT>
__global__ __launch_bounds__(256) void gemm_mfma_kernel(
    const ushort* __restrict__ A, const ushort* __restrict__ Bt,
    const float* __restrict__ bias, ushort* __restrict__ Cb,
    int M, int N, int K) {
    constexpr int MF = BM / 32;          // m-frags of 16 per wave
    constexpr int NF = BN / 32;          // n-frags of 16 per wave
    constexpr int AG = BM / 32;          // A glds per wave (BM/4 rows, 8 rows/gld)
    constexpr int BG = BN / 32;          // B glds per wave
    __shared__ ushort As[BM * 64];
    __shared__ ushort Bs[BN * 64];
    int t = threadIdx.x;
    int lane = t & 63, wid = t >> 6;
    int lg = lane >> 4, lm = lane & 15;

    int nz = gridDim.z, zz = blockIdx.z;
    int klen = K / nz, koff = zz * klen;
    Cb += (size_t)zz * M * N;

    int nx = gridDim.x;
    int nwg = nx * gridDim.y;
    int swz = xcd_swizzle(blockIdx.x + nx * blockIdx.y, nwg);
    int m0 = (swz / nx) * BM, n0 = (swz % nx) * BN;

    int wr = (wid >> 1) * (BM / 2);
    int wc = (wid & 1) * (BN / 2);

    fx4 acc[MF][NF];
    #pragma unroll
    for (int i = 0; i < MF; i++)
        #pragma unroll
        for (int j = 0; j < NF; j++) acc[i][j] = (fx4){0.f, 0.f, 0.f, 0.f};

    int srow = lane >> 3, scol = (lane & 7) * 8;
    const ushort* paw = A + (size_t)(m0 + wid * (BM / 4) + srow) * K + scol + koff;
    ushort* law = As + wid * (BM / 4) * 64;
    const ushort* pbw = Bt + (size_t)(n0 + wid * (BN / 4) + srow) * K + scol + koff;
    ushort* lbw = Bs + wid * (BN / 4) * 64;

    for (int k0 = 0; k0 < klen; k0 += 64) {
        #pragma unroll
        for (int i = 0; i < AG; i++)
            gld_lds16(paw + (size_t)i * 8 * K + k0, law + i * 512);
        #pragma unroll
        for (int i = 0; i < BG; i++)
            gld_lds16(pbw + (size_t)i * 8 * K + k0, lbw + i * 512);
        __syncthreads();
        #pragma unroll
        for (int ks = 0; ks < 2; ks++) {
            s16x8 a[MF], b[NF];
            #pragma unroll
            for (int f = 0; f < MF; f++)
                a[f] = *(const s16x8*)&As[(wr + f * 16 + lm) * 64 + ks * 32 + lg * 8];
            #pragma unroll
            for (int f = 0; f < NF; f++)
                b[f] = *(const s16x8*)&Bs[(wc + f * 16 + lm) * 64 + ks * 32 + lg * 8];
            #pragma unroll
            for (int i = 0; i < MF; i++)
                #pragma unroll
                for (int j = 0; j < NF; j++)
                    acc[i][j] = __builtin_amdgcn_mfma_f32_16x16x32_bf16(a[i], b[j], acc[i][j], 0, 0, 0);
        }
        __syncthreads();
    }
    int crow = lg * 4, ccol = lm;
    #pragma unroll
    for (int i = 0; i < MF; i++) {
        #pragma unroll
        for (int j = 0; j < NF; j++) {
            int col = n0 + wc + j * 16 + ccol;
            float bv_ = (zz == 0) ? bias[col] : 0.f;
            #pragma unroll
            for (int r = 0; r < 4; r++) {
                int row = m0 + wr + i * 16 + crow + r;
                float val = acc[i][j][r] + bv_;
                if (ACT) {
                    float tt = 0.7978845608028654f * (val + 0.044715f * val * val * val);
                    val = val * (1.f / (1.f + __expf(-2.f * tt)));
                }
                Cb[(size_t)row * N + col] = f2bf(val);
            }
        }
    }
}

// ---------------- MFMA flash band attention: QB=64, exp2 softmax, bitmask band ----------------
#define QB 64
#define KTW 64
#define NKT 9
__global__ __launch_bounds__(256, 1) void band_attn_kernel(
    const ushort* __restrict__ qkv, const float* __restrict__ mask,
    ushort* __restrict__ ctxb) {
    __shared__ ushort KV[4 * 64 * 72];     // 36,864 B
    __shared__ ushort Ps[4 * 16 * 64];     //  8,192 B
    __shared__ uint   Msb[18];             //     72 B
    ushort* K0 = KV;
    ushort* V0 = KV + 64 * 72;
    ushort* K1 = KV + 2 * 64 * 72;
    ushort* V1 = KV + 3 * 64 * 72;
    ushort* Qs = K1;

    int bid = blockIdx.x + gridDim.x * blockIdx.y;
    int swz = (bid & 7) * 96 + (bid >> 3);
    int qblk = swz & 63, h = swz >> 6;

    int qbase = qblk * QB;
    int kbase = qbase - WIN;
    int t = threadIdx.x;
    int w = t >> 6, lane = t & 63;
    int lg = lane >> 4, lm = lane & 15;
    int lg4 = lg * 4;
    int wl = w * 16 + lm;          // query offset within block

    int kt_lo = (qbase < WIN) ? ((WIN - qbase) >> 6) : 0;
    int kt_hi = (S_LEN - qbase + WIN) >> 6;
    if (kt_hi > NKT) kt_hi = NKT;

    const ushort* qP = qkv + h * 64;
    const ushort* kP = qkv + HID + h * 64;
    const ushort* vP = qkv + 2 * HID + h * 64;

    // ---- prologue ----
    if (t < 18) Msb[t] = 0u;
    {
        int r = t >> 2, c = (t & 3) * 16;
        const ushort* src = qP + (size_t)(qbase + r) * 2304 + c;
        *(uint4*)&Qs[r * 72 + c]     = *(const uint4*)src;
        *(uint4*)&Qs[r * 72 + c + 8] = *(const uint4*)(src + 8);
    }
    int krow = t >> 2, kcol = (t & 3) * 16;
    int vkey = t & 63, vd0 = (t >> 6) * 16;
    uint4 kr0, kr1, vr0, vr1;
    {
        const ushort* ks = kP + (size_t)(kbase + kt_lo * KTW + krow) * 2304 + kcol;
        kr0 = *(const uint4*)ks; kr1 = *(const uint4*)(ks + 8);
        const ushort* vs = vP + (size_t)(kbase + kt_lo * KTW + vkey) * 2304 + vd0;
        vr0 = *(const uint4*)vs; vr1 = *(const uint4*)(vs + 8);
    }
    __syncthreads();
    for (int i = kt_lo * KTW + t; i < kt_hi * KTW; i += 256)
        if (mask[kbase + i] > 0.5f) atomicOr(&Msb[i >> 5], 1u << (i & 31));
    s16x8 aq0 = *(const s16x8*)&Qs[(w * 16 + lm) * 72 + lg * 8];
    s16x8 aq1 = *(const s16x8*)&Qs[(w * 16 + lm) * 72 + lg * 8 + 32];
    *(uint4*)&K0[krow * 72 + kcol]     = kr0;
    *(uint4*)&K0[krow * 72 + kcol + 8] = kr1;
    {
        union { uint4 u; ushort s[8]; } a, b;
        a.u = vr0; b.u = vr1;
        #pragma unroll
        for (int j = 0; j < 8; j++) V0[(vd0 + j) * 72 + vkey] = a.s[j];
        #pragma unroll
        for (int j = 0; j < 8; j++) V0[(vd0 + 8 + j) * 72 + vkey] = b.s[j];
    }
    __syncthreads();

    float mq = 0.f, lq = 0.f;      // defer-max from 0 (log2 units); lq per-lane partial
    fx4 accO[4];
    #pragma unroll
    for (int rt = 0; rt < 4; rt++) accO[rt] = (fx4){0.f, 0.f, 0.f, 0.f};

    int q0 = qbase + w * 16;
    const fx4 zf = (fx4){0.f, 0.f, 0.f, 0.f};
    int pswz = (lm & 7) << 3;
    int prow = (w * 16 + lm) * 64;

    for (int kt = kt_lo; kt < kt_hi; kt++) {
        bool pre = (kt + 1 < kt_hi);
        if (pre) {
            const ushort* ks = kP + (size_t)(kbase + (kt + 1) * KTW + krow) * 2304 + kcol;
            kr0 = *(const uint4*)ks; kr1 = *(const uint4*)(ks + 8);
            const ushort* vs = vP + (size_t)(kbase + (kt + 1) * KTW + vkey) * 2304 + vd0;
            vr0 = *(const uint4*)vs; vr1 = *(const uint4*)(vs + 8);
        }
        int cur = (kt - kt_lo) & 1;
        const ushort* Kc = cur ? K1 : K0;
        const ushort* Vc = cur ? V1 : V0;
        ushort* Kn = cur ? K0 : K1;
        ushort* Vn = cur ? V0 : V1;

        // combined band + attention-mask bitmask for this tile (per query lane)
        uint64_t mm = ((uint64_t)Msb[kt * 2 + 1] << 32) | (uint64_t)Msb[kt * 2];
        {
            int lo_i = wl - kt * 64;            // in [-512, 63]
            uint64_t bm = ~0ull;
            if (lo_i > 0) bm <<= lo_i;
            int hi = lo_i + 512;                // in [0, 575]
            if (hi < 63) bm &= (2ull << hi) - 1;
            mm &= bm;
        }

        // swapped QK^T (scale*log2e pre-folded into Wq): D[key][query(lm)], log2 units
        fx4 sc[4];
        __builtin_amdgcn_s_setprio(1);
        #pragma unroll
        for (int j = 0; j < 4; j++) {
            s16x8 ak0 = *(const s16x8*)&Kc[(j * 16 + lm) * 72 + lg * 8];
            s16x8 ak1 = *(const s16x8*)&Kc[(j * 16 + lm) * 72 + lg * 8 + 32];
            sc[j] = __builtin_amdgcn_mfma_f32_16x16x32_bf16(ak0, aq0, zf, 0, 0, 0);
            sc[j] = __builtin_amdgcn_mfma_f32_16x16x32_bf16(ak1, aq1, sc[j], 0, 0, 0);
        }
        __builtin_amdgcn_s_setprio(0);

        // tile max; masked path only when any lane has a partial tile
        float tmax = -1e30f;
        int allfull = __all((int)(mm == ~0ull));
        if (allfull) {
            #pragma unroll
            for (int j = 0; j < 4; j++)
                #pragma unroll
                for (int r = 0; r < 4; r++) tmax = fmaxf(tmax, sc[j][r]);
        } else {
            #pragma unroll
            for (int j = 0; j < 4; j++) {
                uint m16 = (uint)(mm >> (j * 16)) & 0xFFFFu;
                #pragma unroll
                for (int r = 0; r < 4; r++) {
                    bool ok = (m16 >> (lg4 + r)) & 1u;
                    sc[j][r] = ok ? sc[j][r] : -1e30f;
                    tmax = fmaxf(tmax, sc[j][r]);
                }
            }
        }
        tmax = fmaxf(tmax, __shfl_xor(tmax, 16, 64));
        tmax = fmaxf(tmax, __shfl_xor(tmax, 32, 64));

        // defer-max: rescale only when max grew beyond threshold (log2 units)
        if (__any((int)(tmax > mq + DEFER_THR))) {
            float nm = fmaxf(mq, tmax);
            float corr = exp2f(mq - nm);
            mq = nm;
            lq *= corr;
            #pragma unroll
            for (int rt = 0; rt < 4; rt++) {
                accO[rt][0] *= corr; accO[rt][1] *= corr;
                accO[rt][2] *= corr; accO[rt][3] *= corr;
            }
        }
        // P = 2^(S - mq) (masked scores underflow to 0); per-lane partial sum
        #pragma unroll
        for (int j = 0; j < 4; j++) {
            float p0 = exp2f(sc[j][0] - mq);
            float p1 = exp2f(sc[j][1] - mq);
            float p2 = exp2f(sc[j][2] - mq);
            float p3 = exp2f(sc[j][3] - mq);
            lq += (p0 + p1) + (p2 + p3);
            uint lo = (uint)f2bf(p0) | ((uint)f2bf(p1) << 16);
            uint hi = (uint)f2bf(p2) | ((uint)f2bf(p3) << 16);
            *(uint2*)&Ps[prow + ((j * 16 + lg * 4) ^ pswz)] = make_uint2(lo, hi);
        }

        asm volatile("s_waitcnt lgkmcnt(0)" ::: "memory");
        // PV: O^T[dim][query]
        s16x8 bp0 = *(const s16x8*)&Ps[prow + ((lg * 8) ^ pswz)];
        s16x8 bp1 = *(const s16x8*)&Ps[prow + ((32 + lg * 8) ^ pswz)];
        __builtin_amdgcn_s_setprio(1);
        #pragma unroll
        for (int rt = 0; rt < 4; rt++) {
            s16x8 av0 = *(const s16x8*)&Vc[(rt * 16 + lm) * 72 + lg * 8];
            s16x8 av1 = *(const s16x8*)&Vc[(rt * 16 + lm) * 72 + lg * 8 + 32];
            accO[rt] = __builtin_amdgcn_mfma_f32_16x16x32_bf16(av0, bp0, accO[rt], 0, 0, 0);
            accO[rt] = __builtin_amdgcn_mfma_f32_16x16x32_bf16(av1, bp1, accO[rt], 0, 0, 0);
        }
        __builtin_amdgcn_s_setprio(0);

        if (pre) {
            *(uint4*)&Kn[krow * 72 + kcol]     = kr0;
            *(uint4*)&Kn[krow * 72 + kcol + 8] = kr1;
            union { uint4 u; ushort s[8]; } a, b;
            a.u = vr0; b.u = vr1;
            #pragma unroll
            for (int j = 0; j < 8; j++) Vn[(vd0 + j) * 72 + vkey] = a.s[j];
            #pragma unroll
            for (int j = 0; j < 8; j++) Vn[(vd0 + 8 + j) * 72 + vkey] = b.s[j];
            __syncthreads();
        }
    }

    lq += __shfl_xor(lq, 16, 64);
    lq += __shfl_xor(lq, 32, 64);
    float inv = 1.f / lq;
    int q = q0 + lm;
    #pragma unroll
    for (int rt = 0; rt < 4; rt++) {
        int dbase = rt * 16 + lg * 4;
        uint2 wv;
        wv.x = (uint)f2bf(accO[rt][0] * inv) | ((uint)f2bf(accO[rt][1] * inv) << 16);
        wv.y = (uint)f2bf(accO[rt][2] * inv) | ((uint)f2bf(accO[rt][3] * inv) << 16);
        *(uint2*)(ctxb + (size_t)q * HID + h * 64 + dbase) = wv;
    }
}

// ---------------- fused heads: split-K partial GEMV (pooled row is bf16) ----------------
__global__ __launch_bounds__(256) void heads_partial_kernel(
    const ushort* __restrict__ x0,
    const float* __restrict__ W0, const float* __restrict__ W1, const float* __restrict__ W2,
    float* __restrict__ p0, float* __restrict__ p1, float* __restrict__ p2) {
    int which = blockIdx.z;
    const float* Wt = which == 0 ? W0 : which == 1 ? W1 : W2;
    float* part     = which == 0 ? p0 : which == 1 ? p1 : p2;
    int N           = which == 0 ? N_ICD : which == 1 ? N_CPT : N_CH;
    if (blockIdx.x * 64 >= N) return;
    __shared__ float red[256];
    int t = threadIdx.x;
    int nn = blockIdx.x * 64 + (t & 63);
    int ks = t >> 6;
    int kc = blockIdx.y;
    int h0 = kc * 96 + ks * 24;
    float s = 0.f;
    if (nn < N) {
        #pragma unroll
        for (int kk = 0; kk < 24; kk++)
            s += bf2f(x0[h0 + kk]) * Wt[(size_t)(h0 + kk) * N + nn];
    }
    red[t] = s;
    __syncthreads();
    if (t < 64 && nn < N)
        part[(size_t)kc * N + nn] = (red[t] + red[t + 64]) + (red[t + 128] + red[t + 192]);
}

// ---------------- fused combine+focal (33 blocks: 16 icd, 16 cpt, 1 ch) ----------------
__global__ __launch_bounds__(256) void heads_focal_kernel(
    const float* __restrict__ p0, const float* __restrict__ p1, const float* __restrict__ p2,
    const float* __restrict__ b0, const float* __restrict__ b1, const float* __restrict__ b2,
    const float* __restrict__ t0, const float* __restrict__ t1, const float* __restrict__ t2,
    float* __restrict__ lg0, float* __restrict__ lg1, float* __restrict__ lg2,
    float* __restrict__ fpart) {
    int b = blockIdx.x;
    int which = b < 16 ? 0 : (b < 32 ? 1 : 2);
    int bi = which == 0 ? b : (which == 1 ? b - 16 : 0);
    int nb = which == 2 ? 1 : 16;
    const float* part  = which == 0 ? p0 : which == 1 ? p1 : p2;
    const float* bias  = which == 0 ? b0 : which == 1 ? b1 : b2;
    const float* tgt   = which == 0 ? t0 : which == 1 ? t1 : t2;
    float* logits      = which == 0 ? lg0 : which == 1 ? lg1 : lg2;
    int N              = which == 0 ? N_ICD : which == 1 ? N_CPT : N_CH;
    __shared__ float red[256];
    int t = threadIdx.x;
    float s = 0.f;
    for (int i = bi * 256 + t; i < N; i += nb * 256) {
        float l = bias[i];
        #pragma unroll
        for (int kc = 0; kc < 8; kc++) l += part[(size_t)kc * N + i];
        logits[i] = l;
        float y = tgt[i];
        float bce = fmaxf(l, 0.f) - l * y + log1pf(expf(-fabsf(l)));
        float pt = expf(-bce);
        float om = 1.f - pt;
        s += om * om * bce;
    }
    red[t] = s;
    __syncthreads();
    for (int o = 128; o > 0; o >>= 1) {
        if (t < o) red[t] += red[t + o];
        __syncthreads();
    }
    if (t == 0) fpart[b] = red[0];
}

__global__ void final_loss_kernel(const float* __restrict__ parts, float* __restrict__ out) {
    if (threadIdx.x == 0 && blockIdx.x == 0) {
        float a = 0.f, b = 0.f, c;
        for (int i = 0; i < 16; i++) a += parts[i];
        for (int i = 0; i < 16; i++) b += parts[16 + i];
        c = parts[32];
        out[0] = a / (float)N_ICD + b / (float)N_CPT + c / (float)N_CH;
    }
}

// ---------------- launch ----------------
extern "C" void kernel_launch(void* const* d_in, const int* in_sizes, int n_in,
                              void* d_out, int out_size, void* d_ws, size_t ws_size,
                              hipStream_t stream) {
    const int*   ids      = (const int*)d_in[0];
    const float* mask     = (const float*)d_in[1];
    const float* icd_lab  = (const float*)d_in[2];
    const float* cpt_lab  = (const float*)d_in[3];
    const float* ch_lab   = (const float*)d_in[4];
    const float* we       = (const float*)d_in[5];
    const float* pe       = (const float*)d_in[6];
    const float* els      = (const float*)d_in[7];
    const float* elb      = (const float*)d_in[8];
    const float* Wq       = (const float*)d_in[9];
    const float* bq       = (const float*)d_in[10];
    const float* Wk       = (const float*)d_in[11];
    const float* bk       = (const float*)d_in[12];
    const float* Wv       = (const float*)d_in[13];
    const float* bv       = (const float*)d_in[14];
    const float* Wo       = (const float*)d_in[15];
    const float* bo       = (const float*)d_in[16];
    const float* l1s      = (const float*)d_in[17];
    const float* l1b      = (const float*)d_in[18];
    const float* Wi       = (const float*)d_in[19];
    const float* bi       = (const float*)d_in[20];
    const float* Wo2      = (const float*)d_in[21];
    const float* bo2      = (const float*)d_in[22];
    const float* l2s      = (const float*)d_in[23];
    const float* l2b      = (const float*)d_in[24];
    const float* W_icd    = (const float*)d_in[25];
    const float* b_icd    = (const float*)d_in[26];
    const float* W_cpt    = (const float*)d_in[27];
    const float* b_cpt    = (const float*)d_in[28];
    const float* W_ch     = (const float*)d_in[29];
    const float* b_ch     = (const float*)d_in[30];

    const size_t SH = (size_t)S_LEN * HID;
    const size_t WW = (size_t)HID * HID;
    const size_t WI = (size_t)HID * FF;

    char* base = (char*)d_ws;
    size_t off = 0;
    auto alloc = [&](size_t bytes) { void* p = base + off; off += (bytes + 255) & ~(size_t)255; return p; };

    float* bqkv  = (float*)alloc(2 * 2304 * 4);
    float* chl   = (float*)alloc(32 * 4);
    float* fpart = (float*)alloc(64 * 4);
    float* hp_icd = (float*)alloc((size_t)8 * N_ICD * 4);
    float* hp_cpt = (float*)alloc((size_t)8 * N_CPT * 4);
    float* hp_ch  = (float*)alloc((size_t)8 * 32 * 4);
    ushort* tmpb    = (ushort*)alloc(2 * SH * 2);   // 2 split-K partial buffers
    ushort* xb      = (ushort*)alloc(SH * 2);
    ushort* qkvb    = (ushort*)alloc((size_t)S_LEN * 2304 * 2);
    ushort* ctxb    = (ushort*)alloc(SH * 2);
    ushort* ffhb    = (ushort*)alloc((size_t)S_LEN * FF * 2);
    ushort* wt_qkvo = (ushort*)alloc((size_t)8 * WW * 2);
    ushort* wt_i    = (ushort*)alloc((size_t)2 * WI * 2);
    ushort* wt_o2   = (ushort*)alloc((size_t)2 * WI * 2);

    float* out = (float*)d_out;
    float* icd_logits = out + 1;
    float* cpt_logits = out + 1 + N_ICD;

    prep_kernel<<<17926, 256, 0, stream>>>(
        Wq, Wk, Wv, Wo, Wi, Wo2, bq, bk, bv, wt_qkvo, wt_i, wt_o2, bqkv,
        ids, we, pe, els, elb, xb);

    for (int l = 0; l < NLAYER; l++) {
        const ushort* wt_qkv_l = wt_qkvo + (size_t)l * 4 * WW;
        const ushort* wt_o_l   = wt_qkvo + (size_t)l * 4 * WW + 3 * WW;
        const ushort* wt_i_l   = wt_i  + (size_t)l * WI;
        const ushort* wt_o2_l  = wt_o2 + (size_t)l * WI;

        gemm_mfma_kernel<64,64,0><<<dim3(2304/64, S_LEN/64, 1), 256, 0, stream>>>(
            xb, wt_qkv_l, bqkv + l * 2304, qkvb, S_LEN, 2304, HID);

        band_attn_kernel<<<dim3(S_LEN/QB, NHEAD), 256, 0, stream>>>(qkvb, mask, ctxb);

        gemm_mfma_kernel<64,64,0><<<dim3(HID/64, S_LEN/64, 2), 256, 0, stream>>>(
            ctxb, wt_o_l, bo + l*HID, tmpb, S_LEN, HID, HID);
        residual_ln_kernel<<<S_LEN/4, 256, 0, stream>>>(xb, tmpb, tmpb + SH, l1s + l*HID, l1b + l*HID);

        gemm_mfma_kernel<64,64,1><<<dim3(FF/64, S_LEN/64, 1), 256, 0, stream>>>(
            xb, wt_i_l, bi + l*FF, ffhb, S_LEN, FF, HID);
        gemm_mfma_kernel<64,64,0><<<dim3(HID/64, S_LEN/64, 2), 256, 0, stream>>>(
            ffhb, wt_o2_l, bo2 + l*HID, tmpb, S_LEN, HID, FF);
        residual_ln_kernel<<<S_LEN/4, 256, 0, stream>>>(xb, tmpb, tmpb + SH, l2s + l*HID, l2b + l*HID);
    }

    heads_partial_kernel<<<dim3((N_ICD + 63) / 64, 8, 3), 256, 0, stream>>>(
        xb, W_icd, W_cpt, W_ch, hp_icd, hp_cpt, hp_ch);
    heads_focal_kernel<<<33, 256, 0, stream>>>(
        hp_icd, hp_cpt, hp_ch, b_icd, b_cpt, b_ch, icd_lab, cpt_lab, ch_lab,
        icd_logits, cpt_logits, chl, fpart);
    final_loss_kernel<<<1, 1, 0, stream>>>(fpart, out);
}

// Round 22
// 365.610 us; speedup vs baseline: 1.0395x; 1.0395x over previous
//
#include <hip/hip_runtime.h>
#include <hip/hip_bf16.h>
#include <math.h>

#define S_LEN 4096
#define HID 768
#define NHEAD 12
#define NLAYER 2
#define WIN 256
#define FF 3072
#define N_ICD 8000
#define N_CPT 5000
#define N_CH 22

typedef short s16x8 __attribute__((ext_vector_type(8)));
typedef float fx4 __attribute__((ext_vector_type(4)));

__device__ __forceinline__ ushort f2bf(float f) {
    union { float f; uint u; } c; c.f = f;
    uint u = c.u + 0x7fffu + ((c.u >> 16) & 1u);
    return (ushort)(u >> 16);
}
__device__ __forceinline__ float bf2f(ushort u) {
    union { uint u; float f; } c; c.u = (uint)u << 16; return c.f;
}

// async global->LDS, 16B per lane; l must be the wave-uniform base (HW adds lane*16)
__device__ __forceinline__ void gld_lds16(const ushort* g, ushort* l) {
    __builtin_amdgcn_global_load_lds(
        (const __attribute__((address_space(1))) unsigned int*)g,
        (__attribute__((address_space(3))) unsigned int*)l, 16, 0, 0);
}

// bijective XCD-chunk swizzle (m204)
__device__ __forceinline__ int xcd_swizzle(int bid, int nwg) {
    int q = nwg >> 3, r = nwg & 7;
    int xcd = bid & 7, idx = bid >> 3;
    return (xcd < r ? xcd * (q + 1) : r * (q + 1) + (xcd - r) * q) + idx;
}

// ---------------- block reduce (deterministic), 256 threads ----------------
__device__ __forceinline__ float breduce(float v, volatile float* red) {
    int t = threadIdx.x;
    #pragma unroll
    for (int o = 32; o > 0; o >>= 1) v += __shfl_down(v, o, 64);
    __syncthreads();
    if ((t & 63) == 0) red[t >> 6] = v;
    __syncthreads();
    return red[0] + red[1] + red[2] + red[3];
}

#define QSCALE 0.1803368801111204f   // 0.125 * log2(e): folded scale for exp2-softmax
#define DEFER_THR 11.5415603f        // 8 * log2(e)

// ---------------- unified prep: weight transposes + bias pack + embed+LN ----------------
// flat 1D grid, exact block counts:
//  [0,4608)        qkvo transposes (8 x 576)
//  [4608,9216)     Wi transposes   (2 x 2304)
//  [9216,13824)    Wo2 transposes  (2 x 2304)
//  [13824,13830)   bias pack       (2 layers x 3)
//  [13830,17926)   embed + LN      (4096 rows)
__global__ __launch_bounds__(256) void prep_kernel(
    const float* __restrict__ Wq, const float* __restrict__ Wk,
    const float* __restrict__ Wv, const float* __restrict__ Wo_,
    const float* __restrict__ Wi, const float* __restrict__ Wo2,
    const float* __restrict__ bq, const float* __restrict__ bk,
    const float* __restrict__ bv,
    ushort* __restrict__ wt_qkvo, ushort* __restrict__ wt_i,
    ushort* __restrict__ wt_o2, float* __restrict__ bqkv,
    const int* __restrict__ ids, const float* __restrict__ we,
    const float* __restrict__ pe, const float* __restrict__ els,
    const float* __restrict__ elb, ushort* __restrict__ xb) {
    const size_t WW = (size_t)HID * HID;
    const size_t WI = (size_t)HID * FF;
    int idx = blockIdx.x;
    int t = threadIdx.x;
    __shared__ float T[32][33];
    __shared__ float red[4];
    if (idx >= 13830) {
        int srow = idx - 13830;
        int id = ids[srow];
        float v[3];
        #pragma unroll
        for (int i = 0; i < 3; i++) {
            int hh = i * 256 + t;
            v[i] = we[(size_t)id * HID + hh] + pe[srow * HID + hh];
        }
        float mean = breduce(v[0] + v[1] + v[2], red) * (1.f / HID);
        __syncthreads();
        float sq = 0.f;
        #pragma unroll
        for (int i = 0; i < 3; i++) { float d = v[i] - mean; sq += d * d; }
        float var = breduce(sq, red) * (1.f / HID);
        float inv = rsqrtf(var + 1e-5f);
        #pragma unroll
        for (int i = 0; i < 3; i++) {
            int hh = i * 256 + t;
            float o = (v[i] - mean) * inv * els[hh] + elb[hh];
            xb[(size_t)srow * HID + hh] = f2bf(o);
        }
        return;
    }
    if (idx >= 13824) {
        int b = idx - 13824;
        int l = b / 3, p = b % 3;
        int i = p * 256 + t;
        if (i < HID) {
            bqkv[l * 2304 + i]           = bq[l * HID + i] * QSCALE;   // scale folded
            bqkv[l * 2304 + HID + i]     = bk[l * HID + i];
            bqkv[l * 2304 + 2 * HID + i] = bv[l * HID + i];
        }
        return;
    }
    const float* in; ushort* out; int K, N, n0, k0;
    float wscale = 1.f;
    if (idx < 4608) {
        int z = idx / 576, r = idx % 576;
        int wsel = z >> 1, l = z & 1;
        in = (wsel == 0 ? Wq : wsel == 1 ? Wk : wsel == 2 ? Wv : Wo_) + (size_t)l * WW;
        out = wt_qkvo + ((size_t)l * 4 + wsel) * WW;
        K = HID; N = HID; n0 = (r % 24) * 32; k0 = (r / 24) * 32;
        if (wsel == 0) wscale = QSCALE;
    } else if (idx < 9216) {
        int r = idx - 4608; int l = r / 2304; r %= 2304;
        in = Wi + (size_t)l * WI; out = wt_i + (size_t)l * WI;
        K = HID; N = FF; n0 = (r % 96) * 32; k0 = (r / 96) * 32;
    } else {
        int r = idx - 9216; int l = r / 2304; r %= 2304;
        in = Wo2 + (size_t)l * WI; out = wt_o2 + (size_t)l * WI;
        K = FF; N = HID; n0 = (r % 24) * 32; k0 = (r / 24) * 32;
    }
    int tx = t & 31, ty = t >> 5;
    #pragma unroll
    for (int i = 0; i < 32; i += 8)
        T[ty + i][tx] = in[(size_t)(k0 + ty + i) * N + n0 + tx];
    __syncthreads();
    #pragma unroll
    for (int i = 0; i < 32; i += 8)
        out[(size_t)(n0 + ty + i) * K + k0 + tx] = f2bf(T[tx][ty + i] * wscale);
}

// ---------------- residual + LN, all-bf16 stream, wave-per-row, 4 rows/block ----------------
__global__ __launch_bounds__(256) void residual_ln_kernel(
    ushort* __restrict__ xb, const ushort* __restrict__ y,
    const float* __restrict__ ls, const float* __restrict__ lb) {
    int row = blockIdx.x * 4 + (threadIdx.x >> 6);
    int lane = threadIdx.x & 63;
    const size_t base = (size_t)row * HID;
    float v[12];
    float s = 0.f;
    #pragma unroll
    for (int i = 0; i < 3; i++) {
        int c = i * 256 + lane * 4;
        ushort4 xv = *(const ushort4*)&xb[base + c];
        ushort4 yv = *(const ushort4*)&y[base + c];
        v[i*4+0] = bf2f(xv.x) + bf2f(yv.x);
        v[i*4+1] = bf2f(xv.y) + bf2f(yv.y);
        v[i*4+2] = bf2f(xv.z) + bf2f(yv.z);
        v[i*4+3] = bf2f(xv.w) + bf2f(yv.w);
        s += (v[i*4+0] + v[i*4+1]) + (v[i*4+2] + v[i*4+3]);
    }
    #pragma unroll
    for (int o = 32; o > 0; o >>= 1) s += __shfl_down(s, o, 64);
    float mean = __shfl(s, 0, 64) * (1.f / HID);
    float sq = 0.f;
    #pragma unroll
    for (int i = 0; i < 12; i++) { v[i] -= mean; sq += v[i] * v[i]; }
    #pragma unroll
    for (int o = 32; o > 0; o >>= 1) sq += __shfl_down(sq, o, 64);
    float inv = rsqrtf(__shfl(sq, 0, 64) * (1.f / HID) + 1e-5f);
    #pragma unroll
    for (int i = 0; i < 3; i++) {
        int c = i * 256 + lane * 4;
        float4 sv = *(const float4*)&ls[c];
        float4 bv_ = *(const float4*)&lb[c];
        ushort4 ov;
        ov.x = f2bf(v[i*4+0] * inv * sv.x + bv_.x);
        ov.y = f2bf(v[i*4+1] * inv * sv.y + bv_.y);
        ov.z = f2bf(v[i*4+2] * inv * sv.z + bv_.z);
        ov.w = f2bf(v[i*4+3] * inv * sv.w + bv_.w);
        *(ushort4*)&xb[base + c] = ov;
    }
}

// ---------------- bf16 MFMA GEMM, global_load_lds staging, BK=64, XCD swizzle ----------------
// 4 waves 2x2; BM=BN=64: each wave 32x32. Single-buffer (round-18 structure).
template<int BM, int BN, int ACT>
__global__ __launch_bounds__(256) void gemm_mfma_kernel(
    const ushort* __restrict__ A, const ushort* __restrict__ Bt,
    const float* __restrict__ bias, ushort* __restrict__ Cb,
    int M, int N, int K) {
    constexpr int MF = BM / 32;          // m-frags of 16 per wave
    constexpr int NF = BN / 32;          // n-frags of 16 per wave
    constexpr int AG = BM / 32;          // A glds per wave (BM/4 rows, 8 rows/gld)
    constexpr int BG = BN / 32;          // B glds per wave
    __shared__ ushort As[BM * 64];
    __shared__ ushort Bs[BN * 64];
    int t = threadIdx.x;
    int lane = t & 63, wid = t >> 6;
    int lg = lane >> 4, lm = lane & 15;

    int nx = gridDim.x;
    int nwg = nx * gridDim.y;
    int swz = xcd_swizzle(blockIdx.x + nx * blockIdx.y, nwg);
    int m0 = (swz / nx) * BM, n0 = (swz % nx) * BN;

    int wr = (wid >> 1) * (BM / 2);
    int wc = (wid & 1) * (BN / 2);

    fx4 acc[MF][NF];
    #pragma unroll
    for (int i = 0; i < MF; i++)
        #pragma unroll
        for (int j = 0; j < NF; j++) acc[i][j] = (fx4){0.f, 0.f, 0.f, 0.f};

    int srow = lane >> 3, scol = (lane & 7) * 8;
    const ushort* paw = A + (size_t)(m0 + wid * (BM / 4) + srow) * K + scol;
    ushort* law = As + wid * (BM / 4) * 64;
    const ushort* pbw = Bt + (size_t)(n0 + wid * (BN / 4) + srow) * K + scol;
    ushort* lbw = Bs + wid * (BN / 4) * 64;

    for (int k0 = 0; k0 < K; k0 += 64) {
        #pragma unroll
        for (int i = 0; i < AG; i++)
            gld_lds16(paw + (size_t)i * 8 * K + k0, law + i * 512);
        #pragma unroll
        for (int i = 0; i < BG; i++)
            gld_lds16(pbw + (size_t)i * 8 * K + k0, lbw + i * 512);
        __syncthreads();
        #pragma unroll
        for (int ks = 0; ks < 2; ks++) {
            s16x8 a[MF], b[NF];
            #pragma unroll
            for (int f = 0; f < MF; f++)
                a[f] = *(const s16x8*)&As[(wr + f * 16 + lm) * 64 + ks * 32 + lg * 8];
            #pragma unroll
            for (int f = 0; f < NF; f++)
                b[f] = *(const s16x8*)&Bs[(wc + f * 16 + lm) * 64 + ks * 32 + lg * 8];
            #pragma unroll
            for (int i = 0; i < MF; i++)
                #pragma unroll
                for (int j = 0; j < NF; j++)
                    acc[i][j] = __builtin_amdgcn_mfma_f32_16x16x32_bf16(a[i], b[j], acc[i][j], 0, 0, 0);
        }
        __syncthreads();
    }
    int crow = lg * 4, ccol = lm;
    #pragma unroll
    for (int i = 0; i < MF; i++) {
        #pragma unroll
        for (int j = 0; j < NF; j++) {
            int col = n0 + wc + j * 16 + ccol;
            float bv_ = bias[col];
            #pragma unroll
            for (int r = 0; r < 4; r++) {
                int row = m0 + wr + i * 16 + crow + r;
                float val = acc[i][j][r] + bv_;
                if (ACT) {
                    float tt = 0.7978845608028654f * (val + 0.044715f * val * val * val);
                    val = val * (1.f / (1.f + __expf(-2.f * tt)));
                }
                Cb[(size_t)row * N + col] = f2bf(val);
            }
        }
    }
}

// ---------------- MFMA flash band attention: QB=64, exp2 softmax, bitmask band ----------------
#define QB 64
#define KTW 64
#define NKT 9
__global__ __launch_bounds__(256, 1) void band_attn_kernel(
    const ushort* __restrict__ qkv, const float* __restrict__ mask,
    ushort* __restrict__ ctxb) {
    __shared__ ushort KV[4 * 64 * 72];     // 36,864 B
    __shared__ ushort Ps[4 * 16 * 64];     //  8,192 B
    __shared__ uint   Msb[18];             //     72 B
    ushort* K0 = KV;
    ushort* V0 = KV + 64 * 72;
    ushort* K1 = KV + 2 * 64 * 72;
    ushort* V1 = KV + 3 * 64 * 72;
    ushort* Qs = K1;

    int bid = blockIdx.x + gridDim.x * blockIdx.y;
    int swz = (bid & 7) * 96 + (bid >> 3);
    int qblk = swz & 63, h = swz >> 6;

    int qbase = qblk * QB;
    int kbase = qbase - WIN;
    int t = threadIdx.x;
    int w = t >> 6, lane = t & 63;
    int lg = lane >> 4, lm = lane & 15;
    int lg4 = lg * 4;
    int wl = w * 16 + lm;          // query offset within block

    int kt_lo = (qbase < WIN) ? ((WIN - qbase) >> 6) : 0;
    int kt_hi = (S_LEN - qbase + WIN) >> 6;
    if (kt_hi > NKT) kt_hi = NKT;

    const ushort* qP = qkv + h * 64;
    const ushort* kP = qkv + HID + h * 64;
    const ushort* vP = qkv + 2 * HID + h * 64;

    // ---- prologue ----
    if (t < 18) Msb[t] = 0u;
    {
        int r = t >> 2, c = (t & 3) * 16;
        const ushort* src = qP + (size_t)(qbase + r) * 2304 + c;
        *(uint4*)&Qs[r * 72 + c]     = *(const uint4*)src;
        *(uint4*)&Qs[r * 72 + c + 8] = *(const uint4*)(src + 8);
    }
    int krow = t >> 2, kcol = (t & 3) * 16;
    int vkey = t & 63, vd0 = (t >> 6) * 16;
    uint4 kr0, kr1, vr0, vr1;
    {
        const ushort* ks = kP + (size_t)(kbase + kt_lo * KTW + krow) * 2304 + kcol;
        kr0 = *(const uint4*)ks; kr1 = *(const uint4*)(ks + 8);
        const ushort* vs = vP + (size_t)(kbase + kt_lo * KTW + vkey) * 2304 + vd0;
        vr0 = *(const uint4*)vs; vr1 = *(const uint4*)(vs + 8);
    }
    __syncthreads();
    for (int i = kt_lo * KTW + t; i < kt_hi * KTW; i += 256)
        if (mask[kbase + i] > 0.5f) atomicOr(&Msb[i >> 5], 1u << (i & 31));
    s16x8 aq0 = *(const s16x8*)&Qs[(w * 16 + lm) * 72 + lg * 8];
    s16x8 aq1 = *(const s16x8*)&Qs[(w * 16 + lm) * 72 + lg * 8 + 32];
    *(uint4*)&K0[krow * 72 + kcol]     = kr0;
    *(uint4*)&K0[krow * 72 + kcol + 8] = kr1;
    {
        union { uint4 u; ushort s[8]; } a, b;
        a.u = vr0; b.u = vr1;
        #pragma unroll
        for (int j = 0; j < 8; j++) V0[(vd0 + j) * 72 + vkey] = a.s[j];
        #pragma unroll
        for (int j = 0; j < 8; j++) V0[(vd0 + 8 + j) * 72 + vkey] = b.s[j];
    }
    __syncthreads();

    float mq = 0.f, lq = 0.f;      // defer-max from 0 (log2 units); lq per-lane partial
    fx4 accO[4];
    #pragma unroll
    for (int rt = 0; rt < 4; rt++) accO[rt] = (fx4){0.f, 0.f, 0.f, 0.f};

    int q0 = qbase + w * 16;
    const fx4 zf = (fx4){0.f, 0.f, 0.f, 0.f};
    int pswz = (lm & 7) << 3;
    int prow = (w * 16 + lm) * 64;

    for (int kt = kt_lo; kt < kt_hi; kt++) {
        bool pre = (kt + 1 < kt_hi);
        if (pre) {
            const ushort* ks = kP + (size_t)(kbase + (kt + 1) * KTW + krow) * 2304 + kcol;
            kr0 = *(const uint4*)ks; kr1 = *(const uint4*)(ks + 8);
            const ushort* vs = vP + (size_t)(kbase + (kt + 1) * KTW + vkey) * 2304 + vd0;
            vr0 = *(const uint4*)vs; vr1 = *(const uint4*)(vs + 8);
        }
        int cur = (kt - kt_lo) & 1;
        const ushort* Kc = cur ? K1 : K0;
        const ushort* Vc = cur ? V1 : V0;
        ushort* Kn = cur ? K0 : K1;
        ushort* Vn = cur ? V0 : V1;

        // combined band + attention-mask bitmask for this tile (per query lane)
        uint64_t mm = ((uint64_t)Msb[kt * 2 + 1] << 32) | (uint64_t)Msb[kt * 2];
        {
            int lo_i = wl - kt * 64;            // in [-512, 63]
            uint64_t bm = ~0ull;
            if (lo_i > 0) bm <<= lo_i;
            int hi = lo_i + 512;                // in [0, 575]
            if (hi < 63) bm &= (2ull << hi) - 1;
            mm &= bm;
        }

        // swapped QK^T (scale*log2e pre-folded into Wq): D[key][query(lm)], log2 units
        fx4 sc[4];
        __builtin_amdgcn_s_setprio(1);
        #pragma unroll
        for (int j = 0; j < 4; j++) {
            s16x8 ak0 = *(const s16x8*)&Kc[(j * 16 + lm) * 72 + lg * 8];
            s16x8 ak1 = *(const s16x8*)&Kc[(j * 16 + lm) * 72 + lg * 8 + 32];
            sc[j] = __builtin_amdgcn_mfma_f32_16x16x32_bf16(ak0, aq0, zf, 0, 0, 0);
            sc[j] = __builtin_amdgcn_mfma_f32_16x16x32_bf16(ak1, aq1, sc[j], 0, 0, 0);
        }
        __builtin_amdgcn_s_setprio(0);

        // tile max; masked path only when any lane has a partial tile
        float tmax = -1e30f;
        int allfull = __all((int)(mm == ~0ull));
        if (allfull) {
            #pragma unroll
            for (int j = 0; j < 4; j++)
                #pragma unroll
                for (int r = 0; r < 4; r++) tmax = fmaxf(tmax, sc[j][r]);
        } else {
            #pragma unroll
            for (int j = 0; j < 4; j++) {
                uint m16 = (uint)(mm >> (j * 16)) & 0xFFFFu;
                #pragma unroll
                for (int r = 0; r < 4; r++) {
                    bool ok = (m16 >> (lg4 + r)) & 1u;
                    sc[j][r] = ok ? sc[j][r] : -1e30f;
                    tmax = fmaxf(tmax, sc[j][r]);
                }
            }
        }
        tmax = fmaxf(tmax, __shfl_xor(tmax, 16, 64));
        tmax = fmaxf(tmax, __shfl_xor(tmax, 32, 64));

        // defer-max: rescale only when max grew beyond threshold (log2 units)
        if (__any((int)(tmax > mq + DEFER_THR))) {
            float nm = fmaxf(mq, tmax);
            float corr = exp2f(mq - nm);
            mq = nm;
            lq *= corr;
            #pragma unroll
            for (int rt = 0; rt < 4; rt++) {
                accO[rt][0] *= corr; accO[rt][1] *= corr;
                accO[rt][2] *= corr; accO[rt][3] *= corr;
            }
        }
        // P = 2^(S - mq) (masked scores underflow to 0); per-lane partial sum
        #pragma unroll
        for (int j = 0; j < 4; j++) {
            float p0 = exp2f(sc[j][0] - mq);
            float p1 = exp2f(sc[j][1] - mq);
            float p2 = exp2f(sc[j][2] - mq);
            float p3 = exp2f(sc[j][3] - mq);
            lq += (p0 + p1) + (p2 + p3);
            uint lo = (uint)f2bf(p0) | ((uint)f2bf(p1) << 16);
            uint hi = (uint)f2bf(p2) | ((uint)f2bf(p3) << 16);
            *(uint2*)&Ps[prow + ((j * 16 + lg * 4) ^ pswz)] = make_uint2(lo, hi);
        }

        asm volatile("s_waitcnt lgkmcnt(0)" ::: "memory");
        // PV: O^T[dim][query]
        s16x8 bp0 = *(const s16x8*)&Ps[prow + ((lg * 8) ^ pswz)];
        s16x8 bp1 = *(const s16x8*)&Ps[prow + ((32 + lg * 8) ^ pswz)];
        __builtin_amdgcn_s_setprio(1);
        #pragma unroll
        for (int rt = 0; rt < 4; rt++) {
            s16x8 av0 = *(const s16x8*)&Vc[(rt * 16 + lm) * 72 + lg * 8];
            s16x8 av1 = *(const s16x8*)&Vc[(rt * 16 + lm) * 72 + lg * 8 + 32];
            accO[rt] = __builtin_amdgcn_mfma_f32_16x16x32_bf16(av0, bp0, accO[rt], 0, 0, 0);
            accO[rt] = __builtin_amdgcn_mfma_f32_16x16x32_bf16(av1, bp1, accO[rt], 0, 0, 0);
        }
        __builtin_amdgcn_s_setprio(0);

        if (pre) {
            *(uint4*)&Kn[krow * 72 + kcol]     = kr0;
            *(uint4*)&Kn[krow * 72 + kcol + 8] = kr1;
            union { uint4 u; ushort s[8]; } a, b;
            a.u = vr0; b.u = vr1;
            #pragma unroll
            for (int j = 0; j < 8; j++) Vn[(vd0 + j) * 72 + vkey] = a.s[j];
            #pragma unroll
            for (int j = 0; j < 8; j++) Vn[(vd0 + 8 + j) * 72 + vkey] = b.s[j];
            __syncthreads();
        }
    }

    lq += __shfl_xor(lq, 16, 64);
    lq += __shfl_xor(lq, 32, 64);
    float inv = 1.f / lq;
    int q = q0 + lm;
    #pragma unroll
    for (int rt = 0; rt < 4; rt++) {
        int dbase = rt * 16 + lg * 4;
        uint2 wv;
        wv.x = (uint)f2bf(accO[rt][0] * inv) | ((uint)f2bf(accO[rt][1] * inv) << 16);
        wv.y = (uint)f2bf(accO[rt][2] * inv) | ((uint)f2bf(accO[rt][3] * inv) << 16);
        *(uint2*)(ctxb + (size_t)q * HID + h * 64 + dbase) = wv;
    }
}

// ---------------- fused heads: split-K partial GEMV (pooled row is bf16) ----------------
__global__ __launch_bounds__(256) void heads_partial_kernel(
    const ushort* __restrict__ x0,
    const float* __restrict__ W0, const float* __restrict__ W1, const float* __restrict__ W2,
    float* __restrict__ p0, float* __restrict__ p1, float* __restrict__ p2) {
    int which = blockIdx.z;
    const float* Wt = which == 0 ? W0 : which == 1 ? W1 : W2;
    float* part     = which == 0 ? p0 : which == 1 ? p1 : p2;
    int N           = which == 0 ? N_ICD : which == 1 ? N_CPT : N_CH;
    if (blockIdx.x * 64 >= N) return;
    __shared__ float red[256];
    int t = threadIdx.x;
    int nn = blockIdx.x * 64 + (t & 63);
    int ks = t >> 6;
    int kc = blockIdx.y;
    int h0 = kc * 96 + ks * 24;
    float s = 0.f;
    if (nn < N) {
        #pragma unroll
        for (int kk = 0; kk < 24; kk++)
            s += bf2f(x0[h0 + kk]) * Wt[(size_t)(h0 + kk) * N + nn];
    }
    red[t] = s;
    __syncthreads();
    if (t < 64 && nn < N)
        part[(size_t)kc * N + nn] = (red[t] + red[t + 64]) + (red[t + 128] + red[t + 192]);
}

// ---------------- fused combine+focal (33 blocks: 16 icd, 16 cpt, 1 ch) ----------------
__global__ __launch_bounds__(256) void heads_focal_kernel(
    const float* __restrict__ p0, const float* __restrict__ p1, const float* __restrict__ p2,
    const float* __restrict__ b0, const float* __restrict__ b1, const float* __restrict__ b2,
    const float* __restrict__ t0, const float* __restrict__ t1, const float* __restrict__ t2,
    float* __restrict__ lg0, float* __restrict__ lg1, float* __restrict__ lg2,
    float* __restrict__ fpart) {
    int b = blockIdx.x;
    int which = b < 16 ? 0 : (b < 32 ? 1 : 2);
    int bi = which == 0 ? b : (which == 1 ? b - 16 : 0);
    int nb = which == 2 ? 1 : 16;
    const float* part  = which == 0 ? p0 : which == 1 ? p1 : p2;
    const float* bias  = which == 0 ? b0 : which == 1 ? b1 : b2;
    const float* tgt   = which == 0 ? t0 : which == 1 ? t1 : t2;
    float* logits      = which == 0 ? lg0 : which == 1 ? lg1 : lg2;
    int N              = which == 0 ? N_ICD : which == 1 ? N_CPT : N_CH;
    __shared__ float red[256];
    int t = threadIdx.x;
    float s = 0.f;
    for (int i = bi * 256 + t; i < N; i += nb * 256) {
        float l = bias[i];
        #pragma unroll
        for (int kc = 0; kc < 8; kc++) l += part[(size_t)kc * N + i];
        logits[i] = l;
        float y = tgt[i];
        float bce = fmaxf(l, 0.f) - l * y + log1pf(expf(-fabsf(l)));
        float pt = expf(-bce);
        float om = 1.f - pt;
        s += om * om * bce;
    }
    red[t] = s;
    __syncthreads();
    for (int o = 128; o > 0; o >>= 1) {
        if (t < o) red[t] += red[t + o];
        __syncthreads();
    }
    if (t == 0) fpart[b] = red[0];
}

__global__ void final_loss_kernel(const float* __restrict__ parts, float* __restrict__ out) {
    if (threadIdx.x == 0 && blockIdx.x == 0) {
        float a = 0.f, b = 0.f, c;
        for (int i = 0; i < 16; i++) a += parts[i];
        for (int i = 0; i < 16; i++) b += parts[16 + i];
        c = parts[32];
        out[0] = a / (float)N_ICD + b / (float)N_CPT + c / (float)N_CH;
    }
}

// ---------------- launch ----------------
extern "C" void kernel_launch(void* const* d_in, const int* in_sizes, int n_in,
                              void* d_out, int out_size, void* d_ws, size_t ws_size,
                              hipStream_t stream) {
    const int*   ids      = (const int*)d_in[0];
    const float* mask     = (const float*)d_in[1];
    const float* icd_lab  = (const float*)d_in[2];
    const float* cpt_lab  = (const float*)d_in[3];
    const float* ch_lab   = (const float*)d_in[4];
    const float* we       = (const float*)d_in[5];
    const float* pe       = (const float*)d_in[6];
    const float* els      = (const float*)d_in[7];
    const float* elb      = (const float*)d_in[8];
    const float* Wq       = (const float*)d_in[9];
    const float* bq       = (const float*)d_in[10];
    const float* Wk       = (const float*)d_in[11];
    const float* bk       = (const float*)d_in[12];
    const float* Wv       = (const float*)d_in[13];
    const float* bv       = (const float*)d_in[14];
    const float* Wo       = (const float*)d_in[15];
    const float* bo       = (const float*)d_in[16];
    const float* l1s      = (const float*)d_in[17];
    const float* l1b      = (const float*)d_in[18];
    const float* Wi       = (const float*)d_in[19];
    const float* bi       = (const float*)d_in[20];
    const float* Wo2      = (const float*)d_in[21];
    const float* bo2      = (const float*)d_in[22];
    const float* l2s      = (const float*)d_in[23];
    const float* l2b      = (const float*)d_in[24];
    const float* W_icd    = (const float*)d_in[25];
    const float* b_icd    = (const float*)d_in[26];
    const float* W_cpt    = (const float*)d_in[27];
    const float* b_cpt    = (const float*)d_in[28];
    const float* W_ch     = (const float*)d_in[29];
    const float* b_ch     = (const float*)d_in[30];

    const size_t SH = (size_t)S_LEN * HID;
    const size_t WW = (size_t)HID * HID;
    const size_t WI = (size_t)HID * FF;

    char* base = (char*)d_ws;
    size_t off = 0;
    auto alloc = [&](size_t bytes) { void* p = base + off; off += (bytes + 255) & ~(size_t)255; return p; };

    float* bqkv  = (float*)alloc(2 * 2304 * 4);
    float* chl   = (float*)alloc(32 * 4);
    float* fpart = (float*)alloc(64 * 4);
    float* hp_icd = (float*)alloc((size_t)8 * N_ICD * 4);
    float* hp_cpt = (float*)alloc((size_t)8 * N_CPT * 4);
    float* hp_ch  = (float*)alloc((size_t)8 * 32 * 4);
    ushort* tmpb    = (ushort*)alloc(SH * 2);
    ushort* xb      = (ushort*)alloc(SH * 2);
    ushort* qkvb    = (ushort*)alloc((size_t)S_LEN * 2304 * 2);
    ushort* ctxb    = (ushort*)alloc(SH * 2);
    ushort* ffhb    = (ushort*)alloc((size_t)S_LEN * FF * 2);
    ushort* wt_qkvo = (ushort*)alloc((size_t)8 * WW * 2);
    ushort* wt_i    = (ushort*)alloc((size_t)2 * WI * 2);
    ushort* wt_o2   = (ushort*)alloc((size_t)2 * WI * 2);

    float* out = (float*)d_out;
    float* icd_logits = out + 1;
    float* cpt_logits = out + 1 + N_ICD;

    prep_kernel<<<17926, 256, 0, stream>>>(
        Wq, Wk, Wv, Wo, Wi, Wo2, bq, bk, bv, wt_qkvo, wt_i, wt_o2, bqkv,
        ids, we, pe, els, elb, xb);

    for (int l = 0; l < NLAYER; l++) {
        const ushort* wt_qkv_l = wt_qkvo + (size_t)l * 4 * WW;
        const ushort* wt_o_l   = wt_qkvo + (size_t)l * 4 * WW + 3 * WW;
        const ushort* wt_i_l   = wt_i  + (size_t)l * WI;
        const ushort* wt_o2_l  = wt_o2 + (size_t)l * WI;

        gemm_mfma_kernel<64,64,0><<<dim3(2304/64, S_LEN/64), 256, 0, stream>>>(
            xb, wt_qkv_l, bqkv + l * 2304, qkvb, S_LEN, 2304, HID);

        band_attn_kernel<<<dim3(S_LEN/QB, NHEAD), 256, 0, stream>>>(qkvb, mask, ctxb);

        gemm_mfma_kernel<64,64,0><<<dim3(HID/64, S_LEN/64), 256, 0, stream>>>(
            ctxb, wt_o_l, bo + l*HID, tmpb, S_LEN, HID, HID);
        residual_ln_kernel<<<S_LEN/4, 256, 0, stream>>>(xb, tmpb, l1s + l*HID, l1b + l*HID);

        gemm_mfma_kernel<64,64,1><<<dim3(FF/64, S_LEN/64), 256, 0, stream>>>(
            xb, wt_i_l, bi + l*FF, ffhb, S_LEN, FF, HID);
        gemm_mfma_kernel<64,64,0><<<dim3(HID/64, S_LEN/64), 256, 0, stream>>>(
            ffhb, wt_o2_l, bo2 + l*HID, tmpb, S_LEN, HID, FF);
        residual_ln_kernel<<<S_LEN/4, 256, 0, stream>>>(xb, tmpb, l2s + l*HID, l2b + l*HID);
    }

    heads_partial_kernel<<<dim3((N_ICD + 63) / 64, 8, 3), 256, 0, stream>>>(
        xb, W_icd, W_cpt, W_ch, hp_icd, hp_cpt, hp_ch);
    heads_focal_kernel<<<33, 256, 0, stream>>>(
        hp_icd, hp_cpt, hp_ch, b_icd, b_cpt, b_ch, icd_lab, cpt_lab, ch_lab,
        icd_logits, cpt_logits, chl, fpart);
    final_loss_kernel<<<1, 1, 0, stream>>>(fpart, out);
}